// Round 2
// baseline (244.474 us; speedup 1.0000x reference)
//
#include <hip/hip_runtime.h>
#include <hip/hip_bf16.h>
#include <math.h>

// Problem constants (B=2, H=12, S=2048, D=64, hash_code_len=8)
#define NB 2
#define NH 12
#define NS 2048
#define ND 64
#define NBH (NB * NH)
#define LDK 72          // padded LDS row length in bf16 elems (144 B, 16B-aligned)

typedef __attribute__((ext_vector_type(8))) short short8;   // 8 bf16 = 4 VGPRs (MFMA A/B frag)
typedef __attribute__((ext_vector_type(4))) float floatx4;  // MFMA C/D frag

__device__ __forceinline__ unsigned short f32_to_bf16(float f) {
  unsigned int u = __float_as_uint(f);
  u += 0x7fffu + ((u >> 16) & 1u);   // round-to-nearest-even
  return (unsigned short)(u >> 16);
}

// f(d) = (1 - acos(d)/pi)^... base: 1 - acos(d)/pi via A&S 4.4.45:
// acos(x) = sqrt(1-x)*(a0 + a1 x + a2 x^2 + a3 x^3), x in [0,1], |err|<=7e-5.
// Coefficients pre-divided by pi. For d<0: f = u; d>=0: f = 1-u.
__device__ __forceinline__ float yoso_f(float d) {
  const float c0 = 0.49996030f;    // 1.5707288/pi
  const float c1 = -0.06751822f;   // -0.2121144/pi
  const float c2 = 0.02363774f;    // 0.0742610/pi
  const float c3 = -0.00596174f;   // -0.0187293/pi
  float a = fminf(fabsf(d), 1.0f);
  float p = fmaf(fmaf(fmaf(c3, a, c2), a, c1), a, c0);
  float u = sqrtf(1.0f - a) * p;   // = acos(|d|)/pi
  return (d >= 0.0f) ? (1.0f - u) : u;
}

// ---------------------------------------------------------------------------
// Prep 1: l2-normalize Q and K rows (D=64) and cast to bf16.
// 16 lanes per row (float4 per lane), 16 rows per 256-thread block.
// Rows: [0, NBH*NS) -> Q, then K.
// ---------------------------------------------------------------------------
__global__ __launch_bounds__(256) void prep_qk(
    const float* __restrict__ Q, const float* __restrict__ K,
    unsigned short* __restrict__ qn, unsigned short* __restrict__ kn) {
  int row = blockIdx.x * 16 + (threadIdx.x >> 4);
  int li  = threadIdx.x & 15;
  const float* src = Q;
  unsigned short* dst = qn;
  if (row >= NBH * NS) { src = K; dst = kn; row -= NBH * NS; }
  float4 v = *(const float4*)(src + (size_t)row * ND + li * 4);
  float ss = v.x * v.x + v.y * v.y + v.z * v.z + v.w * v.w;
  ss += __shfl_xor(ss, 1, 64);
  ss += __shfl_xor(ss, 2, 64);
  ss += __shfl_xor(ss, 4, 64);
  ss += __shfl_xor(ss, 8, 64);
  float rn = 1.0f / fmaxf(sqrtf(ss), 1e-12f);
  ushort4 o;
  o.x = f32_to_bf16(v.x * rn);
  o.y = f32_to_bf16(v.y * rn);
  o.z = f32_to_bf16(v.z * rn);
  o.w = f32_to_bf16(v.w * rn);
  *(ushort4*)(dst + (size_t)row * ND + li * 4) = o;
}

// ---------------------------------------------------------------------------
// Prep 2: V [bh][t][d] fp32 -> Vt [bh][d][p] bf16, transposed AND k-permuted
// within each 64-t tile: position p holds t(p) = (p&3)*16 + (p>>2), i.e.
// p(t) = (t&15)*4 + (t>>4). MFMA sums over k, so any permutation is legal as
// long as the W writes in yoso_main use the same one (they do: p = lq*4+fn).
// ---------------------------------------------------------------------------
__global__ __launch_bounds__(256) void prep_v(
    const float* __restrict__ V, unsigned short* __restrict__ Vt) {
  int bh = blockIdx.x >> 5;          // NS/64 = 32 tiles per bh
  int t0 = (blockIdx.x & 31) * 64;
  __shared__ float sT[64][65];       // [d][t], padded
  int tid = threadIdx.x;
  int tr = tid >> 2;                 // t within tile, 0..63
  int dc = (tid & 3) * 16;           // d start
  const float* vp = V + ((size_t)bh * NS + t0 + tr) * ND + dc;
  #pragma unroll
  for (int j = 0; j < 16; j += 4) {
    float4 v = *(const float4*)(vp + j);
    sT[dc + j + 0][tr] = v.x;
    sT[dc + j + 1][tr] = v.y;
    sT[dc + j + 2][tr] = v.z;
    sT[dc + j + 3][tr] = v.w;
  }
  __syncthreads();
  int dr = tid >> 2;                 // d row, 0..63
  int ttg = (tid & 3) * 4;           // group of 4 tt values
  unsigned short* op = Vt + ((size_t)bh * ND + dr) * NS + t0;
  #pragma unroll
  for (int g = 0; g < 4; ++g) {
    int tt = ttg + g;                // t & 15
    ushort4 o;                       // positions tt*4 + j <-> t = j*16 + tt
    o.x = f32_to_bf16(sT[dr][0 * 16 + tt]);
    o.y = f32_to_bf16(sT[dr][1 * 16 + tt]);
    o.z = f32_to_bf16(sT[dr][2 * 16 + tt]);
    o.w = f32_to_bf16(sT[dr][3 * 16 + tt]);
    *(ushort4*)(op + tt * 4) = o;
  }
}

// ---------------------------------------------------------------------------
// Main: per (bh, 64-query tile) block, 4 waves; wave w owns query rows
// [w*16, w*16+16). Loop over 32 key tiles of 64:
//   scores = qn @ kn^T (MFMA bf16) -> transform (poly-acos/^8/key-mask, fp32)
//   -> W bf16 via LDS (C-layout -> A-layout, permuted-k packed b64 writes)
//   -> X += W @ V (MFMA bf16, sV in same permuted-k order).
// Next K/V tile is prefetched into registers during compute.
// Epilogue: query mask, l2norm (16-lane shuffle), + depthwise conv3 (fp32 V).
// ---------------------------------------------------------------------------
__global__ __launch_bounds__(256) void yoso_main(
    const unsigned short* __restrict__ qn, const unsigned short* __restrict__ kn,
    const unsigned short* __restrict__ Vt, const float* __restrict__ V,
    const float* __restrict__ mask, const float* __restrict__ conv_w,
    float* __restrict__ out) {
  int bh = blockIdx.x >> 5;              // 32 q-tiles per bh
  int b  = bh / NH;
  int h  = bh % NH;
  int s0 = (blockIdx.x & 31) * 64;

  __shared__ unsigned short sQ[64 * LDK];
  __shared__ unsigned short sK[64 * LDK];
  __shared__ unsigned short sV[64 * LDK];   // V tile, [d][p] permuted-k
  __shared__ unsigned short sW[64 * LDK];   // transformed scores, [q][p] permuted-k

  int tid  = threadIdx.x;
  int wv   = tid >> 6;       // wave 0..3
  int lane = tid & 63;
  int lq   = lane & 15;      // n/m index within 16
  int quad = lane >> 4;      // 0..3

  // staging geometry: each thread owns 2 rows (p=0,1) x 16B
  int str = tid >> 3;              // 0..31 (+32 for p=1)
  int stc = (tid & 7) * 8;         // bf16 col

  // Load qn tile once.
  {
    const unsigned short* qp = qn + ((size_t)bh * NS + s0) * ND;
    #pragma unroll
    for (int p = 0; p < 2; ++p) {
      int r = p * 32 + str;
      *(uint4*)(&sQ[r * LDK + stc]) = *(const uint4*)(qp + r * ND + stc);
    }
  }

  float w0 = conv_w[h * 3 + 0], w1 = conv_w[h * 3 + 1], w2 = conv_w[h * 3 + 2];

  floatx4 acc[4];
  #pragma unroll
  for (int i = 0; i < 4; ++i) acc[i] = (floatx4){0.f, 0.f, 0.f, 0.f};

  const unsigned short* kbase = kn + (size_t)bh * NS * ND;
  const unsigned short* vtb   = Vt + (size_t)bh * ND * NS;

  // prefetch tile 0 into registers
  uint4 kreg[2], vreg[2];
  #pragma unroll
  for (int p = 0; p < 2; ++p) {
    int r = p * 32 + str;
    kreg[p] = *(const uint4*)(kbase + (size_t)r * ND + stc);
    vreg[p] = *(const uint4*)(vtb + (size_t)r * NS + stc);
  }

  for (int kt = 0; kt < NS / 64; ++kt) {
    int t0 = kt * 64;
    __syncthreads();   // all waves done reading previous sK/sV
    #pragma unroll
    for (int p = 0; p < 2; ++p) {
      int r = p * 32 + str;
      *(uint4*)(&sK[r * LDK + stc]) = kreg[p];
      *(uint4*)(&sV[r * LDK + stc]) = vreg[p];
    }
    // issue next tile's loads; vmcnt wait lands at next iteration's LDS write
    if (kt + 1 < NS / 64) {
      int t1 = t0 + 64;
      #pragma unroll
      for (int p = 0; p < 2; ++p) {
        int r = p * 32 + str;
        kreg[p] = *(const uint4*)(kbase + (size_t)(t1 + r) * ND + stc);
        vreg[p] = *(const uint4*)(vtb + (size_t)r * NS + t1 + stc);
      }
    }
    __syncthreads();

    // scores: rows q = wv*16+m, cols t = 0..63
    floatx4 sc[4];
    #pragma unroll
    for (int i = 0; i < 4; ++i) sc[i] = (floatx4){0.f, 0.f, 0.f, 0.f};
    #pragma unroll
    for (int kk = 0; kk < 2; ++kk) {
      short8 a = *(const short8*)(&sQ[(wv * 16 + lq) * LDK + kk * 32 + quad * 8]);
      #pragma unroll
      for (int fn = 0; fn < 4; ++fn) {
        short8 bf = *(const short8*)(&sK[(fn * 16 + lq) * LDK + kk * 32 + quad * 8]);
        sc[fn] = __builtin_amdgcn_mfma_f32_16x16x32_bf16(a, bf, sc[fn], 0, 0, 0);
      }
    }

    // transform + key mask; C-layout value (q = quad*4+r, t = fn*16+lq)
    // -> sW position p = lq*4 + fn  (permuted-k, matches sV layout),
    // packed 4 bf16 per r -> one b64 write.
    float km[4];
    #pragma unroll
    for (int fn = 0; fn < 4; ++fn) km[fn] = mask[b * NS + t0 + fn * 16 + lq];
    #pragma unroll
    for (int r = 0; r < 4; ++r) {
      ushort4 wp;
      #pragma unroll
      for (int fn = 0; fn < 4; ++fn) {
        float f = yoso_f(sc[fn][r]);
        float f2 = f * f;
        float f4 = f2 * f2;
        float w = f4 * f4 * km[fn];
        ((unsigned short*)&wp)[fn] = f32_to_bf16(w);
      }
      *(ushort4*)(&sW[(wv * 16 + quad * 4 + r) * LDK + lq * 4]) = wp;
    }
    // Wave reads back only its own rows of sW -> no cross-wave barrier needed.

    // X += W @ V : A = sW rows (q, k=p), B = sV rows (n=d, k=p), same perm.
    #pragma unroll
    for (int kk = 0; kk < 2; ++kk) {
      short8 a = *(const short8*)(&sW[(wv * 16 + lq) * LDK + kk * 32 + quad * 8]);
      #pragma unroll
      for (int fn = 0; fn < 4; ++fn) {
        short8 bf = *(const short8*)(&sV[(fn * 16 + lq) * LDK + kk * 32 + quad * 8]);
        acc[fn] = __builtin_amdgcn_mfma_f32_16x16x32_bf16(a, bf, acc[fn], 0, 0, 0);
      }
    }
  }

  // Epilogue: query mask, l2norm over D (row lives in the 16 lanes of this quad
  // group, 4 values per lane), then + depthwise conv3 from exact fp32 V.
  const float* vb = V + (size_t)bh * NS * ND;
  #pragma unroll
  for (int r = 0; r < 4; ++r) {
    int q = quad * 4 + r;
    int s = s0 + wv * 16 + q;
    float qm = mask[b * NS + s];
    float xv[4];
    float ss = 0.f;
    #pragma unroll
    for (int fn = 0; fn < 4; ++fn) {
      float v = acc[fn][r] * qm;
      xv[fn] = v;
      ss += v * v;
    }
    ss += __shfl_xor(ss, 1, 64);
    ss += __shfl_xor(ss, 2, 64);
    ss += __shfl_xor(ss, 4, 64);
    ss += __shfl_xor(ss, 8, 64);
    float rn = 1.0f / fmaxf(sqrtf(ss), 1e-12f);
    #pragma unroll
    for (int fn = 0; fn < 4; ++fn) {
      int d = fn * 16 + lq;
      const float* vcol = vb + d;
      float cv = w1 * vcol[(size_t)s * ND] * mask[b * NS + s];
      if (s > 0)      cv += w0 * vcol[(size_t)(s - 1) * ND] * mask[b * NS + s - 1];
      if (s < NS - 1) cv += w2 * vcol[(size_t)(s + 1) * ND] * mask[b * NS + s + 1];
      out[((size_t)bh * NS + s) * ND + d] = xv[fn] * rn + cv;
    }
  }
}

// ---------------------------------------------------------------------------
extern "C" void kernel_launch(void* const* d_in, const int* in_sizes, int n_in,
                              void* d_out, int out_size, void* d_ws, size_t ws_size,
                              hipStream_t stream) {
  const float* Q      = (const float*)d_in[0];
  const float* K      = (const float*)d_in[1];
  const float* V      = (const float*)d_in[2];
  const float* mask   = (const float*)d_in[3];
  const float* conv_w = (const float*)d_in[4];
  float* out = (float*)d_out;

  // Workspace layout (bf16): qn | kn | Vt, each NBH*NS*ND elems.
  const size_t seg = (size_t)NBH * NS * ND * sizeof(unsigned short);  // 6.29 MB
  unsigned short* qn = (unsigned short*)d_ws;
  unsigned short* kn = (unsigned short*)((char*)d_ws + seg);
  unsigned short* Vt = (unsigned short*)((char*)d_ws + 2 * seg);

  prep_qk<<<(2 * NBH * NS) / 16, 256, 0, stream>>>(Q, K, qn, kn);
  prep_v<<<NBH * (NS / 64), 256, 0, stream>>>(V, Vt);
  yoso_main<<<NBH * (NS / 64), 256, 0, stream>>>(qn, kn, Vt, V, mask, conv_w, out);
}

// Round 3
// 210.603 us; speedup vs baseline: 1.1608x; 1.1608x over previous
//
#include <hip/hip_runtime.h>
#include <hip/hip_bf16.h>
#include <math.h>

// Problem constants (B=2, H=12, S=2048, D=64, hash_code_len=8)
#define NB 2
#define NH 12
#define NS 2048
#define ND 64
#define NBH (NB * NH)
#define TILE_USHORT 4096        // one 64x64 bf16 tile image = 8 KB
#define QK_BLOCKS 6144          // prep: 2*NBH*NS rows / 16 rows per block
#define V_BLOCKS (NBH * 32)     // 768

typedef __attribute__((ext_vector_type(8))) short short8;   // MFMA A/B frag
typedef __attribute__((ext_vector_type(4))) float floatx4;  // MFMA C/D frag

__device__ __forceinline__ unsigned short f32_to_bf16_rne(float f) {
  unsigned int u = __float_as_uint(f);
  u += 0x7fffu + ((u >> 16) & 1u);
  return (unsigned short)(u >> 16);
}

// pack two f32 -> two bf16 (truncate) in ONE v_perm_b32.
// Downward bias (~2^-9 rel) is uniform on W and cancels under the final l2norm.
__device__ __forceinline__ unsigned int pack_bf16_trunc(float lo, float hi) {
  return __builtin_amdgcn_perm(__float_as_uint(hi), __float_as_uint(lo), 0x07060302);
}

// async global->LDS, 16B per lane; LDS dest = uniform base + lane*16.
__device__ __forceinline__ void dma16(const unsigned short* g, unsigned short* l) {
  __builtin_amdgcn_global_load_lds(
      (const __attribute__((address_space(1))) void*)g,
      (__attribute__((address_space(3))) void*)l, 16, 0, 0);
}

// 1 - acos(d)/pi via A&S 4.4.45 (|err| <= 7e-5 rad / pi)
__device__ __forceinline__ float yoso_f(float d) {
  const float c0 = 0.49996030f;
  const float c1 = -0.06751822f;
  const float c2 = 0.02363774f;
  const float c3 = -0.00596174f;
  float a = fminf(fabsf(d), 1.0f);
  float p = fmaf(fmaf(fmaf(c3, a, c2), a, c1), a, c0);
  float u = sqrtf(1.0f - a) * p;
  return (d >= 0.0f) ? (1.0f - u) : u;
}

// ---------------------------------------------------------------------------
// Fused prep: blocks [0,QK_BLOCKS) l2-normalize Q/K rows -> swizzled bf16 tile
// images; blocks [QK_BLOCKS, +V_BLOCKS) transpose+permute V -> Vt images.
// Image layout per (bh,tile): row r (64 bf16 = 8 chunks of 8), chunk c stored
// at c' = c ^ (r&7). This is the exact LDS byte image (DMA-able, and MFMA
// fragment reads are bank-uniform).
// ---------------------------------------------------------------------------
__global__ __launch_bounds__(256) void prep_all(
    const float* __restrict__ Q, const float* __restrict__ K,
    const float* __restrict__ V,
    unsigned short* __restrict__ qimg, unsigned short* __restrict__ kimg,
    unsigned short* __restrict__ vimg) {
  int blk = blockIdx.x;
  if (blk < QK_BLOCKS) {
    int row = blk * 16 + (threadIdx.x >> 4);
    int li  = threadIdx.x & 15;
    const float* src = Q;
    unsigned short* dst = qimg;
    if (row >= NBH * NS) { src = K; dst = kimg; row -= NBH * NS; }
    float4 v = *(const float4*)(src + (size_t)row * ND + li * 4);
    float ss = v.x * v.x + v.y * v.y + v.z * v.z + v.w * v.w;
    ss += __shfl_xor(ss, 1, 64);
    ss += __shfl_xor(ss, 2, 64);
    ss += __shfl_xor(ss, 4, 64);
    ss += __shfl_xor(ss, 8, 64);
    float rn = 1.0f / fmaxf(sqrtf(ss), 1e-12f);
    ushort4 o;
    o.x = f32_to_bf16_rne(v.x * rn);
    o.y = f32_to_bf16_rne(v.y * rn);
    o.z = f32_to_bf16_rne(v.z * rn);
    o.w = f32_to_bf16_rne(v.w * rn);
    int bh = row >> 11;            // / NS
    int s  = row & (NS - 1);
    int kt = s >> 6, r = s & 63;
    size_t off = (size_t)(bh * 32 + kt) * TILE_USHORT +
                 r * 64 + (((li >> 1) ^ (r & 7)) * 8) + (li & 1) * 4;
    *(ushort4*)(dst + off) = o;
  } else {
    int vb = blk - QK_BLOCKS;
    int bh = vb >> 5, kt = vb & 31, t0 = kt * 64;
    __shared__ float sT[64][65];   // [d][t]
    int tid = threadIdx.x;
    int tr = tid >> 2;             // t within tile
    int dc = (tid & 3) * 16;       // d start
    const float* vp = V + ((size_t)bh * NS + t0 + tr) * ND + dc;
    #pragma unroll
    for (int j = 0; j < 16; j += 4) {
      float4 v = *(const float4*)(vp + j);
      sT[dc + j + 0][tr] = v.x;
      sT[dc + j + 1][tr] = v.y;
      sT[dc + j + 2][tr] = v.z;
      sT[dc + j + 3][tr] = v.w;
    }
    __syncthreads();
    int dr = tid >> 2;             // d row
    int ttg = (tid & 3) * 4;
    unsigned short* op = vimg + (size_t)(bh * 32 + kt) * TILE_USHORT;
    #pragma unroll
    for (int g = 0; g < 4; ++g) {
      int tt = ttg + g;            // t & 15; position p = tt*4 + j <-> t = j*16+tt
      ushort4 o;
      o.x = f32_to_bf16_rne(sT[dr][0 * 16 + tt]);
      o.y = f32_to_bf16_rne(sT[dr][1 * 16 + tt]);
      o.z = f32_to_bf16_rne(sT[dr][2 * 16 + tt]);
      o.w = f32_to_bf16_rne(sT[dr][3 * 16 + tt]);
      *(ushort4*)(op + dr * 64 + (((tt >> 1) ^ (dr & 7)) * 8) + (tt & 1) * 4) = o;
    }
  }
}

// ---------------------------------------------------------------------------
// Main. Block = (bh, 64-q tile), 4 waves. Wave w: qh = w&1 (q rows qh*32..+31),
// kp = w>>1 (key tiles kt = 2*ss + kp). Per super-iter ss: DMA-stage key tiles
// 2ss and 2ss+1 (K and V images), then each wave alone computes a full 64x64
// key tile for its 32 q rows: QK MFMA (Q frags in regs) -> transform -> own sW
// -> WV MFMA. Epilogue: k-half reduction via LDS, l2norm, + conv3, store.
// ---------------------------------------------------------------------------
__global__ __launch_bounds__(256, 3) void yoso_main(
    const unsigned short* __restrict__ qimg, const unsigned short* __restrict__ kimg,
    const unsigned short* __restrict__ vimg, const float* __restrict__ V,
    const float* __restrict__ mask, const float* __restrict__ conv_w,
    float* __restrict__ out) {
  int bh = blockIdx.x >> 5;
  int b  = bh / NH;
  int h  = bh % NH;
  int qt = blockIdx.x & 31;
  int s0 = qt * 64;

  __shared__ unsigned short sK[2][TILE_USHORT];   // 16 KB
  __shared__ unsigned short sV[2][TILE_USHORT];   // 16 KB
  __shared__ unsigned short sW[4][32 * 64];       // 16 KB, per-wave regions

  int tid  = threadIdx.x;
  int wv   = tid >> 6;
  int lane = tid & 63;
  int lq   = lane & 15;
  int quad = lane >> 4;
  int qh   = wv & 1;
  int kp   = wv >> 1;
  int swz  = lq & 7;

  // Loop-invariant Q fragments straight from the swizzled global image.
  uint4 qfrag[2][2];   // [su][kk]
  {
    const unsigned short* qtile = qimg + (size_t)(bh * 32 + qt) * TILE_USHORT;
    #pragma unroll
    for (int su = 0; su < 2; ++su)
      #pragma unroll
      for (int kk = 0; kk < 2; ++kk) {
        int R = qh * 32 + su * 16 + lq;
        qfrag[su][kk] = *(const uint4*)(qtile + R * 64 + (((kk * 4 + quad) ^ swz) * 8));
      }
  }

  float w0 = conv_w[h * 3 + 0], w1 = conv_w[h * 3 + 1], w2 = conv_w[h * 3 + 2];

  floatx4 acc[2][4];
  #pragma unroll
  for (int su = 0; su < 2; ++su)
    #pragma unroll
    for (int fn = 0; fn < 4; ++fn) acc[su][fn] = (floatx4){0.f, 0.f, 0.f, 0.f};

  const unsigned short* kb  = kimg + (size_t)bh * 32 * TILE_USHORT;
  const unsigned short* vbI = vimg + (size_t)bh * 32 * TILE_USHORT;

  // staging assignment: wave 0/1 -> K tiles (parity wv&1), wave 2/3 -> V tiles
  const unsigned short* stage_g0 = (wv < 2) ? kb : vbI;
  unsigned short* stage_l = (wv < 2) ? &sK[wv & 1][0] : &sV[wv & 1][0];
  int stage_par = wv & 1;

  unsigned short* myW = &sW[wv][0];

  for (int ss = 0; ss < 16; ++ss) {
    __syncthreads();   // everyone done with previous tiles
    {
      const unsigned short* g =
          stage_g0 + (size_t)(ss * 2 + stage_par) * TILE_USHORT + lane * 8;
      unsigned short* l = stage_l;
      #pragma unroll
      for (int c = 0; c < 8; ++c) dma16(g + c * 512, l + c * 512);
    }
    __syncthreads();   // DMA drained (vmcnt(0) at barrier)

    int kt = ss * 2 + kp;
    const unsigned short* myK = &sK[kp][0];
    const unsigned short* myV = &sV[kp][0];

    // --- QK^T: 32q x 64t ---
    floatx4 sc[2][4];
    #pragma unroll
    for (int su = 0; su < 2; ++su)
      #pragma unroll
      for (int fn = 0; fn < 4; ++fn) sc[su][fn] = (floatx4){0.f, 0.f, 0.f, 0.f};
    #pragma unroll
    for (int kk = 0; kk < 2; ++kk) {
      short8 bk[4];
      #pragma unroll
      for (int fn = 0; fn < 4; ++fn)
        bk[fn] = *(const short8*)(myK + (fn * 16 + lq) * 64 + (((kk * 4 + quad) ^ swz) * 8));
      #pragma unroll
      for (int su = 0; su < 2; ++su) {
        short8 a = *(const short8*)&qfrag[su][kk];
        #pragma unroll
        for (int fn = 0; fn < 4; ++fn)
          sc[su][fn] = __builtin_amdgcn_mfma_f32_16x16x32_bf16(a, bk[fn], sc[su][fn], 0, 0, 0);
      }
    }

    // --- transform + key mask -> own sW (permuted-k positions p = lq*4+fn) ---
    float km[4];
    #pragma unroll
    for (int fn = 0; fn < 4; ++fn) km[fn] = mask[b * NS + kt * 64 + fn * 16 + lq];
    #pragma unroll
    for (int su = 0; su < 2; ++su)
      #pragma unroll
      for (int r = 0; r < 4; ++r) {
        float wvals[4];
        #pragma unroll
        for (int fn = 0; fn < 4; ++fn) {
          float f = yoso_f(sc[su][fn][r]);
          float f2 = f * f;
          float f4 = f2 * f2;
          wvals[fn] = f4 * f4 * km[fn];
        }
        uint2 wp;
        wp.x = pack_bf16_trunc(wvals[0], wvals[1]);
        wp.y = pack_bf16_trunc(wvals[2], wvals[3]);
        int row = su * 16 + quad * 4 + r;
        *(uint2*)(myW + row * 64 + (((lq >> 1) ^ (row & 7)) * 8) + (lq & 1) * 4) = wp;
      }

    // --- X += W @ V ---
    #pragma unroll
    for (int kk = 0; kk < 2; ++kk) {
      short8 bv[4];
      #pragma unroll
      for (int fn = 0; fn < 4; ++fn)
        bv[fn] = *(const short8*)(myV + (fn * 16 + lq) * 64 + (((kk * 4 + quad) ^ swz) * 8));
      #pragma unroll
      for (int su = 0; su < 2; ++su) {
        short8 a = *(const short8*)(myW + (su * 16 + lq) * 64 + (((kk * 4 + quad) ^ swz) * 8));
        #pragma unroll
        for (int fn = 0; fn < 4; ++fn)
          acc[su][fn] = __builtin_amdgcn_mfma_f32_16x16x32_bf16(a, bv[fn], acc[su][fn], 0, 0, 0);
      }
    }
  }

  // --- k-half reduction across wave pairs (qh,0) <-> (qh,1) via LDS ---
  __syncthreads();
  float* xch = (float*)&sK[0][0];   // 4 regions x 1024 floats (16 KB)
  {
    int suw = 1 - kp;               // export the su block the partner will finish
    float* wr = xch + wv * 1024;
    #pragma unroll
    for (int r = 0; r < 4; ++r)
      #pragma unroll
      for (int fn = 0; fn < 4; ++fn)
        wr[(quad * 4 + r) * 64 + fn * 16 + lq] = acc[suw][fn][r];
  }
  __syncthreads();
  {
    const float* rd = xch + (wv ^ 2) * 1024;
    #pragma unroll
    for (int r = 0; r < 4; ++r)
      #pragma unroll
      for (int fn = 0; fn < 4; ++fn)
        acc[kp][fn][r] += rd[(quad * 4 + r) * 64 + fn * 16 + lq];
  }

  // --- epilogue: rows su = kp; query mask, l2norm, + conv3, store ---
  const float* vfull = V + (size_t)bh * NS * ND;
  #pragma unroll
  for (int r = 0; r < 4; ++r) {
    int s = s0 + qh * 32 + kp * 16 + quad * 4 + r;
    float qm = mask[b * NS + s];
    float xv[4];
    float ssum = 0.f;
    #pragma unroll
    for (int fn = 0; fn < 4; ++fn) {
      float x = acc[kp][fn][r] * qm;
      xv[fn] = x;
      ssum += x * x;
    }
    ssum += __shfl_xor(ssum, 1, 64);
    ssum += __shfl_xor(ssum, 2, 64);
    ssum += __shfl_xor(ssum, 4, 64);
    ssum += __shfl_xor(ssum, 8, 64);
    float rn = 1.0f / fmaxf(sqrtf(ssum), 1e-12f);
    #pragma unroll
    for (int fn = 0; fn < 4; ++fn) {
      int d = fn * 16 + lq;
      const float* vcol = vfull + d;
      float cv = w1 * vcol[(size_t)s * ND] * qm;
      if (s > 0)      cv += w0 * vcol[(size_t)(s - 1) * ND] * mask[b * NS + s - 1];
      if (s < NS - 1) cv += w2 * vcol[(size_t)(s + 1) * ND] * mask[b * NS + s + 1];
      out[((size_t)bh * NS + s) * ND + d] = xv[fn] * rn + cv;
    }
  }
}

// ---------------------------------------------------------------------------
extern "C" void kernel_launch(void* const* d_in, const int* in_sizes, int n_in,
                              void* d_out, int out_size, void* d_ws, size_t ws_size,
                              hipStream_t stream) {
  const float* Q      = (const float*)d_in[0];
  const float* K      = (const float*)d_in[1];
  const float* V      = (const float*)d_in[2];
  const float* mask   = (const float*)d_in[3];
  const float* conv_w = (const float*)d_in[4];
  float* out = (float*)d_out;

  const size_t seg = (size_t)NBH * NS * ND * sizeof(unsigned short);  // 6.29 MB
  unsigned short* qimg = (unsigned short*)d_ws;
  unsigned short* kimg = (unsigned short*)((char*)d_ws + seg);
  unsigned short* vimg = (unsigned short*)((char*)d_ws + 2 * seg);

  prep_all<<<QK_BLOCKS + V_BLOCKS, 256, 0, stream>>>(Q, K, V, qimg, kimg, vimg);
  yoso_main<<<NBH * 32, 256, 0, stream>>>(qimg, kimg, vimg, V, mask, conv_w, out);
}

// Round 4
// 149.194 us; speedup vs baseline: 1.6386x; 1.4116x over previous
//
#include <hip/hip_runtime.h>
#include <hip/hip_bf16.h>
#include <math.h>

// Problem constants (B=2, H=12, S=2048, D=64, hash_code_len=8)
#define NB 2
#define NH 12
#define NS 2048
#define ND 64
#define NBH (NB * NH)
#define TILE_USHORT 4096        // one 64x64 bf16 tile image = 8 KB
#define QK_BLOCKS 6144          // prep: 2*NBH*NS rows / 16 rows per block
#define V_BLOCKS (NBH * 32)     // 768

typedef __attribute__((ext_vector_type(8))) short short8;   // MFMA A/B frag
typedef __attribute__((ext_vector_type(4))) float floatx4;  // MFMA C/D frag

__device__ __forceinline__ unsigned short f32_to_bf16_rne(float f) {
  unsigned int u = __float_as_uint(f);
  u += 0x7fffu + ((u >> 16) & 1u);
  return (unsigned short)(u >> 16);
}

// pack two f32 -> two bf16 (truncate) in ONE v_perm_b32 (lo -> low half).
__device__ __forceinline__ unsigned int pack_bf16_trunc(float lo, float hi) {
  return __builtin_amdgcn_perm(__float_as_uint(hi), __float_as_uint(lo), 0x07060302);
}

// async global->LDS, 16B per lane; LDS dest = uniform base + lane*16.
__device__ __forceinline__ void dma16(const unsigned short* g, unsigned short* l) {
  __builtin_amdgcn_global_load_lds(
      (const __attribute__((address_space(1))) void*)g,
      (__attribute__((address_space(3))) void*)l, 16, 0, 0);
}

// exact-ish fallback: 1 - acos(d)/pi via A&S 4.4.45 (valid on full [-1,1])
__device__ __forceinline__ float yoso_f_exact(float d) {
  const float c0 = 0.49996030f;
  const float c1 = -0.06751822f;
  const float c2 = 0.02363774f;
  const float c3 = -0.00596174f;
  float a = fminf(fabsf(d), 1.0f);
  float p = fmaf(fmaf(fmaf(c3, a, c2), a, c1), a, c0);
  float u = sqrtf(1.0f - a) * p;
  return (d >= 0.0f) ? (1.0f - u) : u;
}

// ---------------------------------------------------------------------------
// Fused prep.
// Blocks [0,QK_BLOCKS): l2-normalize Q/K rows -> swizzled bf16 tile images
//   (row r, chunk c of 8 bf16 stored at c^(r&7)).
// Blocks [QK_BLOCKS,+V_BLOCKS): V [t][d] -> vA image [d][pos] where position
//   pos = c*8 + 4w + i  holds  t = 32*(c>>2) + 16*w + 4*(c&3) + i
//   (the k-position->t permutation that matches the register-resident W^T
//   B-operand in yoso_main), chunk-swizzled c^(d&7).
// ---------------------------------------------------------------------------
__global__ __launch_bounds__(256) void prep_all(
    const float* __restrict__ Q, const float* __restrict__ K,
    const float* __restrict__ V,
    unsigned short* __restrict__ qimg, unsigned short* __restrict__ kimg,
    unsigned short* __restrict__ vimg) {
  int blk = blockIdx.x;
  if (blk < QK_BLOCKS) {
    int row = blk * 16 + (threadIdx.x >> 4);
    int li  = threadIdx.x & 15;
    const float* src = Q;
    unsigned short* dst = qimg;
    if (row >= NBH * NS) { src = K; dst = kimg; row -= NBH * NS; }
    float4 v = *(const float4*)(src + (size_t)row * ND + li * 4);
    float ss = v.x * v.x + v.y * v.y + v.z * v.z + v.w * v.w;
    ss += __shfl_xor(ss, 1, 64);
    ss += __shfl_xor(ss, 2, 64);
    ss += __shfl_xor(ss, 4, 64);
    ss += __shfl_xor(ss, 8, 64);
    float rn = 1.0f / fmaxf(sqrtf(ss), 1e-12f);
    ushort4 o;
    o.x = f32_to_bf16_rne(v.x * rn);
    o.y = f32_to_bf16_rne(v.y * rn);
    o.z = f32_to_bf16_rne(v.z * rn);
    o.w = f32_to_bf16_rne(v.w * rn);
    int bh = row >> 11;            // / NS
    int s  = row & (NS - 1);
    int kt = s >> 6, r = s & 63;
    size_t off = (size_t)(bh * 32 + kt) * TILE_USHORT +
                 r * 64 + (((li >> 1) ^ (r & 7)) * 8) + (li & 1) * 4;
    *(ushort4*)(dst + off) = o;
  } else {
    int vb = blk - QK_BLOCKS;
    int bh = vb >> 5, kt = vb & 31, t0 = kt * 64;
    __shared__ float sT[64][65];   // [d][t]
    int tid = threadIdx.x;
    int tr = tid >> 2;             // t within tile
    int dc = (tid & 3) * 16;       // d start
    const float* vp = V + ((size_t)bh * NS + t0 + tr) * ND + dc;
    #pragma unroll
    for (int j = 0; j < 16; j += 4) {
      float4 v = *(const float4*)(vp + j);
      sT[dc + j + 0][tr] = v.x;
      sT[dc + j + 1][tr] = v.y;
      sT[dc + j + 2][tr] = v.z;
      sT[dc + j + 3][tr] = v.w;
    }
    __syncthreads();
    int dr = tid >> 2;             // d row, 0..63
    unsigned short* op = vimg + (size_t)(bh * 32 + kt) * TILE_USHORT + dr * 64;
    #pragma unroll
    for (int g = 0; g < 4; ++g) {
      int combo = (tid & 3) * 4 + g;   // 0..15
      int c = combo >> 1;              // chunk 0..7
      int w = combo & 1;               // half within chunk
      int tb = 32 * (c >> 2) + 16 * w + 4 * (c & 3);
      ushort4 o;
      o.x = f32_to_bf16_rne(sT[dr][tb + 0]);
      o.y = f32_to_bf16_rne(sT[dr][tb + 1]);
      o.z = f32_to_bf16_rne(sT[dr][tb + 2]);
      o.w = f32_to_bf16_rne(sT[dr][tb + 3]);
      *(ushort4*)(op + ((c ^ (dr & 7)) * 8) + 4 * w) = o;
    }
  }
}

// ---------------------------------------------------------------------------
// Main. Block = (bh, 64-q tile), 4 waves. Wave w: qh = w&1 (q rows qh*32..+31),
// kp = w>>1 (key tiles kt = 2*ss+kp). Per iter: DMA-stage K/V tiles, then:
//   MFMA#1: S^T = K·Q^T  (D[m=t][n=q], q on lanes)
//   transform in registers (poly asin/pi, ^8, key mask)
//   MFMA#2: X^T += V^T·W^T  (W^T is the transform output — no LDS round-trip;
//           the k-position->t permutation is baked into the V image)
// Epilogue: k-parity reduction via LDS, query mask, l2norm, + conv3, store.
// ---------------------------------------------------------------------------
__global__ __launch_bounds__(256, 3) void yoso_main(
    const unsigned short* __restrict__ qimg, const unsigned short* __restrict__ kimg,
    const unsigned short* __restrict__ vimg, const float* __restrict__ V,
    const float* __restrict__ mask, const float* __restrict__ conv_w,
    float* __restrict__ out) {
  int bh = blockIdx.x >> 5;
  int b  = bh / NH;
  int h  = bh % NH;
  int qt = blockIdx.x & 31;
  int s0 = qt * 64;

  __shared__ unsigned short sK[2][TILE_USHORT];   // 16 KB
  __shared__ unsigned short sV[2][TILE_USHORT];   // 16 KB

  int tid  = threadIdx.x;
  int wv   = tid >> 6;
  int lane = tid & 63;
  int lq   = lane & 15;
  int quad = lane >> 4;
  int qh   = wv & 1;
  int kp   = wv >> 1;
  int swz  = lq & 7;

  // Loop-invariant Q fragments (B-operand: n=q on lq, k=d chunks).
  uint4 qfrag[2][2];   // [su][kk]
  {
    const unsigned short* qtile = qimg + (size_t)(bh * 32 + qt) * TILE_USHORT;
    #pragma unroll
    for (int su = 0; su < 2; ++su)
      #pragma unroll
      for (int kk = 0; kk < 2; ++kk) {
        int R = qh * 32 + su * 16 + lq;
        qfrag[su][kk] = *(const uint4*)(qtile + R * 64 + (((kk * 4 + quad) ^ swz) * 8));
      }
  }

  float w0 = conv_w[h * 3 + 0], w1 = conv_w[h * 3 + 1], w2 = conv_w[h * 3 + 2];

  floatx4 acc[2][4];   // [su][fd]: X^T, d = fd*16 + quad*4 + r, q = su*16+lq
  #pragma unroll
  for (int su = 0; su < 2; ++su)
    #pragma unroll
    for (int fd = 0; fd < 4; ++fd) acc[su][fd] = (floatx4){0.f, 0.f, 0.f, 0.f};

  const unsigned short* kb  = kimg + (size_t)bh * 32 * TILE_USHORT;
  const unsigned short* vbI = vimg + (size_t)bh * 32 * TILE_USHORT;

  // staging: wave 0/1 -> K tiles (parity wv&1), wave 2/3 -> V tiles
  const unsigned short* stage_g0 = (wv < 2) ? kb : vbI;
  unsigned short* stage_l = (wv < 2) ? &sK[wv & 1][0] : &sV[wv & 1][0];
  int stage_par = wv & 1;

  // asin(x)/pi Taylor coefficients (odd, to x^11), P(y), y=x^2
  const float P0 = 0.3183098862f;
  const float P1 = 0.0530516477f;
  const float P2 = 0.0238732415f;
  const float P3 = 0.0142098402f;
  const float P4 = 0.0096701727f;
  const float P5 = 0.0071212906f;

  for (int ss = 0; ss < 16; ++ss) {
    __syncthreads();
    {
      const unsigned short* g =
          stage_g0 + (size_t)(ss * 2 + stage_par) * TILE_USHORT + lane * 8;
      #pragma unroll
      for (int c = 0; c < 8; ++c) dma16(g + c * 512, stage_l + c * 512);
    }
    __syncthreads();

    int kt = ss * 2 + kp;
    const unsigned short* myK = &sK[kp][0];
    const unsigned short* myV = &sV[kp][0];

    // --- MFMA #1: S^T = K · Q^T  (A = K-frag m=t, B = Q-frag n=q) ---
    floatx4 sc[2][4];   // [su][ft]: t = ft*16 + quad*4 + r, q = su*16+lq
    #pragma unroll
    for (int su = 0; su < 2; ++su)
      #pragma unroll
      for (int ft = 0; ft < 4; ++ft) sc[su][ft] = (floatx4){0.f, 0.f, 0.f, 0.f};
    #pragma unroll
    for (int kk = 0; kk < 2; ++kk) {
      short8 bk[4];
      #pragma unroll
      for (int ft = 0; ft < 4; ++ft)
        bk[ft] = *(const short8*)(myK + (ft * 16 + lq) * 64 + (((kk * 4 + quad) ^ swz) * 8));
      #pragma unroll
      for (int su = 0; su < 2; ++su) {
        short8 bq = *(const short8*)&qfrag[su][kk];
        #pragma unroll
        for (int ft = 0; ft < 4; ++ft)
          sc[su][ft] = __builtin_amdgcn_mfma_f32_16x16x32_bf16(bk[ft], bq, sc[su][ft], 0, 0, 0);
      }
    }

    // --- transform (registers only) ---
    // key mask: t = kt*64 + ft*16 + quad*4 + r -> float4 per ft (lane-uniform per quad)
    const float4* mp = (const float4*)(mask + b * NS + kt * 64) + quad;
    floatx4 warr[2][4];
    float mx = 0.f;
    #pragma unroll
    for (int su = 0; su < 2; ++su)
      #pragma unroll
      for (int ft = 0; ft < 4; ++ft) {
        floatx4 a = sc[su][ft];
        mx = fmaxf(mx, fmaxf(fmaxf(fabsf(a[0]), fabsf(a[1])),
                             fmaxf(fabsf(a[2]), fabsf(a[3]))));
      }
    if (__builtin_expect(__any(mx > 0.82f), 0)) {
      // exact path (rare): full-range acos form
      #pragma unroll
      for (int ft = 0; ft < 4; ++ft) {
        float4 km4 = mp[ft * 4];
        #pragma unroll
        for (int su = 0; su < 2; ++su) {
          floatx4 wv4;
          #pragma unroll
          for (int r = 0; r < 4; ++r) {
            float f = yoso_f_exact(sc[su][ft][r]);
            float f2 = f * f;
            float f4 = f2 * f2;
            wv4[r] = f4 * f4;
          }
          wv4[0] *= km4.x; wv4[1] *= km4.y; wv4[2] *= km4.z; wv4[3] *= km4.w;
          warr[su][ft] = wv4;
        }
      }
    } else {
      #pragma unroll
      for (int ft = 0; ft < 4; ++ft) {
        float4 km4s = mp[ft * 4];
        floatx4 km4 = (floatx4){km4s.x, km4s.y, km4s.z, km4s.w};
        #pragma unroll
        for (int su = 0; su < 2; ++su) {
          floatx4 d = sc[su][ft];
          floatx4 y = d * d;
          floatx4 p = ((((P5 * y + P4) * y + P3) * y + P2) * y + P1) * y + P0;
          floatx4 f = p * d + 0.5f;
          floatx4 f2 = f * f;
          floatx4 f4 = f2 * f2;
          warr[su][ft] = f4 * f4 * km4;
        }
      }
    }

    // --- MFMA #2: X^T += V^T · W^T ---
    // B-frag (n=q, k-pos quad*8+j) for kk2 = concat(pack(warr[su][2kk2]), pack(warr[su][2kk2+1]))
    #pragma unroll
    for (int kk2 = 0; kk2 < 2; ++kk2) {
      short8 av[4];
      #pragma unroll
      for (int fd = 0; fd < 4; ++fd)
        av[fd] = *(const short8*)(myV + (fd * 16 + lq) * 64 + (((kk2 * 4 + quad) ^ swz) * 8));
      #pragma unroll
      for (int su = 0; su < 2; ++su) {
        uint4 u;
        u.x = pack_bf16_trunc(warr[su][2 * kk2][0], warr[su][2 * kk2][1]);
        u.y = pack_bf16_trunc(warr[su][2 * kk2][2], warr[su][2 * kk2][3]);
        u.z = pack_bf16_trunc(warr[su][2 * kk2 + 1][0], warr[su][2 * kk2 + 1][1]);
        u.w = pack_bf16_trunc(warr[su][2 * kk2 + 1][2], warr[su][2 * kk2 + 1][3]);
        short8 bw = *(short8*)&u;
        #pragma unroll
        for (int fd = 0; fd < 4; ++fd)
          acc[su][fd] = __builtin_amdgcn_mfma_f32_16x16x32_bf16(av[fd], bw, acc[su][fd], 0, 0, 0);
      }
    }
  }

  // --- k-parity reduction across wave pairs (qh,0) <-> (qh,1) via LDS ---
  __syncthreads();
  float* xch = (float*)&sK[0][0];   // 4 regions x 1024 floats (16 KB)
  {
    float* wr = xch + wv * 1024;    // export su = 1-kp (partner keeps that su)
    #pragma unroll
    for (int fd = 0; fd < 4; ++fd)
      #pragma unroll
      for (int r = 0; r < 4; ++r)
        wr[lq * 64 + fd * 16 + quad * 4 + r] = acc[1 - kp][fd][r];
  }
  __syncthreads();
  {
    const float* rd = xch + (wv ^ 2) * 1024;
    #pragma unroll
    for (int fd = 0; fd < 4; ++fd)
      #pragma unroll
      for (int r = 0; r < 4; ++r)
        acc[kp][fd][r] += rd[lq * 64 + fd * 16 + quad * 4 + r];
  }

  // --- epilogue: this wave finishes q = s0 + qh*32 + kp*16 + lq ---
  int s = s0 + qh * 32 + kp * 16 + lq;
  float qm  = mask[b * NS + s];
  float qm0 = (s > 0) ? mask[b * NS + s - 1] : 0.f;
  float qm2 = (s < NS - 1) ? mask[b * NS + s + 1] : 0.f;
  float ssum = 0.f;
  #pragma unroll
  for (int fd = 0; fd < 4; ++fd)
    #pragma unroll
    for (int r = 0; r < 4; ++r) {
      float x = acc[kp][fd][r] * qm;
      acc[kp][fd][r] = x;
      ssum += x * x;
    }
  ssum += __shfl_xor(ssum, 16, 64);
  ssum += __shfl_xor(ssum, 32, 64);
  float rn = 1.0f / fmaxf(sqrtf(ssum), 1e-12f);

  const float* vfull = V + ((size_t)bh * NS + s) * ND;
  #pragma unroll
  for (int fd = 0; fd < 4; ++fd) {
    int d = fd * 16 + quad * 4;
    float4 vc1 = *(const float4*)(vfull + d);
    float4 cv;
    cv.x = w1 * vc1.x * qm; cv.y = w1 * vc1.y * qm;
    cv.z = w1 * vc1.z * qm; cv.w = w1 * vc1.w * qm;
    if (s > 0) {
      float4 vc0 = *(const float4*)(vfull - ND + d);
      cv.x += w0 * vc0.x * qm0; cv.y += w0 * vc0.y * qm0;
      cv.z += w0 * vc0.z * qm0; cv.w += w0 * vc0.w * qm0;
    }
    if (s < NS - 1) {
      float4 vc2 = *(const float4*)(vfull + ND + d);
      cv.x += w2 * vc2.x * qm2; cv.y += w2 * vc2.y * qm2;
      cv.z += w2 * vc2.z * qm2; cv.w += w2 * vc2.w * qm2;
    }
    float4 o;
    o.x = acc[kp][fd][0] * rn + cv.x;
    o.y = acc[kp][fd][1] * rn + cv.y;
    o.z = acc[kp][fd][2] * rn + cv.z;
    o.w = acc[kp][fd][3] * rn + cv.w;
    *(float4*)(out + ((size_t)bh * NS + s) * ND + d) = o;
  }
}

// ---------------------------------------------------------------------------
extern "C" void kernel_launch(void* const* d_in, const int* in_sizes, int n_in,
                              void* d_out, int out_size, void* d_ws, size_t ws_size,
                              hipStream_t stream) {
  const float* Q      = (const float*)d_in[0];
  const float* K      = (const float*)d_in[1];
  const float* V      = (const float*)d_in[2];
  const float* mask   = (const float*)d_in[3];
  const float* conv_w = (const float*)d_in[4];
  float* out = (float*)d_out;

  const size_t seg = (size_t)NBH * NS * ND * sizeof(unsigned short);  // 6.29 MB
  unsigned short* qimg = (unsigned short*)d_ws;
  unsigned short* kimg = (unsigned short*)((char*)d_ws + seg);
  unsigned short* vimg = (unsigned short*)((char*)d_ws + 2 * seg);

  prep_all<<<QK_BLOCKS + V_BLOCKS, 256, 0, stream>>>(Q, K, V, qimg, kimg, vimg);
  yoso_main<<<NBH * 32, 256, 0, stream>>>(qimg, kimg, vimg, V, mask, conv_w, out);
}